// Round 12
// baseline (462.438 us; speedup 1.0000x reference)
//
#include <hip/hip_runtime.h>
#include <math.h>

// TiSASRec forward on MI355X — round 11:
//  - attn reverted to R9 exact form (measured best: 47.6us/dispatch).
//    R10's float4 LDS softmax caused 674K bank conflicts (21x) -> regression.
//  - transpose_kernel eliminated (6 -> 5 launches): W matrices read row-major
//    via per-lane float4 row streams (L1-resident), tK_emb read direct in
//    qt_tail via float4 register-transpose. Same fp32 summation orders.
// B=32, L=200, D=64, H=2, dh=32, NL=2.
#define BB 32
#define LLEN 200
#define DD 64
#define HH 2
#define NLAYER 2
#define BLD (BB * LLEN * DD)
#define TSPAN1 366   // TIME_SPAN+1

__device__ inline float waveSum(float v) {
#pragma unroll
    for (int off = 32; off > 0; off >>= 1) v += __shfl_xor(v, off);
    return v;
}
__device__ inline float halfSum(float v) {
    v += __shfl_xor(v, 1);
    v += __shfl_xor(v, 2);
    v += __shfl_xor(v, 4);
    v += __shfl_xor(v, 8);
    v += __shfl_xor(v, 16);
    return v;
}
__device__ inline float halfMax(float v) {
    v = fmaxf(v, __shfl_xor(v, 1));
    v = fmaxf(v, __shfl_xor(v, 2));
    v = fmaxf(v, __shfl_xor(v, 4));
    v = fmaxf(v, __shfl_xor(v, 8));
    v = fmaxf(v, __shfl_xor(v, 16));
    return v;
}

// row-major 64x64 matvec: acc += dot(W[d][:], xsrc[:]) with exact j-ascending
// fp32 order; lane streams its own row via float4 (L1-resident).
__device__ inline float rowdot(const float* __restrict__ W, int d,
                               const float* __restrict__ xsrc, float acc) {
    const float4* Wr = (const float4*)(W + d * DD);
    const float4* xr = (const float4*)xsrc;
#pragma unroll
    for (int jj = 0; jj < 16; ++jj) {
        float4 w4 = Wr[jj];
        float4 x4 = xr[jj];
        acc = fmaf(w4.x, x4.x, acc);
        acc = fmaf(w4.y, x4.y, acc);
        acc = fmaf(w4.z, x4.z, acc);
        acc = fmaf(w4.w, x4.w, acc);
    }
    return acc;
}

// qt tail: block computed Qsh[4][64] for rows base..base+3; thread t owns
// bucket t; Qt[row][h*366+t] = sum_{d in head h} Qsh[r][d] * tK_emb[t][d]
__device__ inline void qt_tail(const float (*Qsh)[DD],
                               const float* __restrict__ tK_emb,
                               float* __restrict__ Qt_g, int base) {
    int tid = threadIdx.x;
    for (int t = tid; t < TSPAN1; t += 256) {
        const float4* tk4 = (const float4*)(tK_emb + t * DD);
        float a0 = 0, a1 = 0, a2 = 0, a3 = 0;
#pragma unroll
        for (int dd = 0; dd < 8; ++dd) {       // head 0: d = 0..31
            float4 v = tk4[dd];
            const float4 q0 = *(const float4*)&Qsh[0][dd * 4];
            const float4 q1 = *(const float4*)&Qsh[1][dd * 4];
            const float4 q2 = *(const float4*)&Qsh[2][dd * 4];
            const float4 q3 = *(const float4*)&Qsh[3][dd * 4];
            a0 = fmaf(v.x, q0.x, a0); a0 = fmaf(v.y, q0.y, a0);
            a0 = fmaf(v.z, q0.z, a0); a0 = fmaf(v.w, q0.w, a0);
            a1 = fmaf(v.x, q1.x, a1); a1 = fmaf(v.y, q1.y, a1);
            a1 = fmaf(v.z, q1.z, a1); a1 = fmaf(v.w, q1.w, a1);
            a2 = fmaf(v.x, q2.x, a2); a2 = fmaf(v.y, q2.y, a2);
            a2 = fmaf(v.z, q2.z, a2); a2 = fmaf(v.w, q2.w, a2);
            a3 = fmaf(v.x, q3.x, a3); a3 = fmaf(v.y, q3.y, a3);
            a3 = fmaf(v.z, q3.z, a3); a3 = fmaf(v.w, q3.w, a3);
        }
        Qt_g[(base + 0) * (2 * TSPAN1) + t] = a0;
        Qt_g[(base + 1) * (2 * TSPAN1) + t] = a1;
        Qt_g[(base + 2) * (2 * TSPAN1) + t] = a2;
        Qt_g[(base + 3) * (2 * TSPAN1) + t] = a3;
        float b0 = 0, b1 = 0, b2 = 0, b3 = 0;
#pragma unroll
        for (int dd = 8; dd < 16; ++dd) {      // head 1: d = 32..63
            float4 v = tk4[dd];
            const float4 q0 = *(const float4*)&Qsh[0][dd * 4];
            const float4 q1 = *(const float4*)&Qsh[1][dd * 4];
            const float4 q2 = *(const float4*)&Qsh[2][dd * 4];
            const float4 q3 = *(const float4*)&Qsh[3][dd * 4];
            b0 = fmaf(v.x, q0.x, b0); b0 = fmaf(v.y, q0.y, b0);
            b0 = fmaf(v.z, q0.z, b0); b0 = fmaf(v.w, q0.w, b0);
            b1 = fmaf(v.x, q1.x, b1); b1 = fmaf(v.y, q1.y, b1);
            b1 = fmaf(v.z, q1.z, b1); b1 = fmaf(v.w, q1.w, b1);
            b2 = fmaf(v.x, q2.x, b2); b2 = fmaf(v.y, q2.y, b2);
            b2 = fmaf(v.z, q2.z, b2); b2 = fmaf(v.w, q2.w, b2);
            b3 = fmaf(v.x, q3.x, b3); b3 = fmaf(v.y, q3.y, b3);
            b3 = fmaf(v.z, q3.z, b3); b3 = fmaf(v.w, q3.w, b3);
        }
        Qt_g[(base + 0) * (2 * TSPAN1) + TSPAN1 + t] = b0;
        Qt_g[(base + 1) * (2 * TSPAN1) + TSPAN1 + t] = b1;
        Qt_g[(base + 2) * (2 * TSPAN1) + TSPAN1 + t] = b2;
        Qt_g[(base + 3) * (2 * TSPAN1) + TSPAN1 + t] = b3;
    }
}

// Layer-0 entry + fused qt: 4 rows/block, wave per row. Embedding fused.
__global__ void ln_qkv_kernel(const int* __restrict__ log_ids,
                              const float* __restrict__ item_emb,
                              const float* __restrict__ g,
                              const float* __restrict__ bln,
                              const float* __restrict__ Wq, const float* __restrict__ bq,
                              const float* __restrict__ Wk, const float* __restrict__ bk,
                              const float* __restrict__ Wv, const float* __restrict__ bv,
                              const float* __restrict__ posK,
                              const float* __restrict__ posV,
                              const float* __restrict__ tK_emb,
                              float* __restrict__ q,
                              float* __restrict__ Q, float* __restrict__ K,
                              float* __restrict__ V,
                              float* __restrict__ Qt_g) {
    __shared__ float qs[4][DD], xs[4][DD], Qsh[4][DD];
    int tid = threadIdx.x;
    int wid = tid >> 6, d = tid & 63;
    int row = blockIdx.x * 4 + wid;
    int l = row % LLEN;
    int id = log_ids[row];
    float xv = (id == 0) ? 0.0f : item_emb[id * DD + d] * 8.0f;  // sqrt(64)*keep
    xs[wid][d] = xv;
    float m = waveSum(xv) * (1.0f / 64.0f);
    float c = xv - m;
    float var = waveSum(c * c) * (1.0f / 64.0f);
    float qv = (c / sqrtf(var + 1e-8f)) * g[d] + bln[d];
    qs[wid][d] = qv;
    q[row * DD + d] = qv;
    float aq = rowdot(Wq, d, qs[wid], bq[d]);
    float ak = rowdot(Wk, d, xs[wid], bk[d]);
    float av = rowdot(Wv, d, xs[wid], bv[d]);
    Q[row * DD + d] = aq;
    K[row * DD + d] = ak + posK[l * DD + d];
    V[row * DD + d] = av + posV[l * DD + d];
    Qsh[wid][d] = aq;
    __syncthreads();
    qt_tail(Qsh, tK_emb, Qt_g, blockIdx.x * 4);
}

// Attention: exact R9 structure (best measured). wave-per-query
// {i,99-i,100+i,199-i}; per-wave phases; qt_s staged; 4-key score groups.
__global__ void attn_kernel(const float* __restrict__ Q,
                            const float* __restrict__ Keff,
                            const float* __restrict__ Veff,
                            const int* __restrict__ log_times,
                            const float* __restrict__ Qt_g,
                            const float* __restrict__ tV_emb,
                            float* __restrict__ out) {
    __shared__ int t_s[LLEN];
    __shared__ float sc[4][HH][LLEN];
    __shared__ unsigned short tm_s[4][LLEN];
    __shared__ float qt_s[4][2 * TSPAN1];

    int tid = threadIdx.x;
    int wid = tid >> 6;
    int lane = tid & 63;
    int bi = blockIdx.x / 50;
    int i = blockIdx.x % 50;
    int qi = (wid == 0) ? i : (wid == 1) ? (99 - i) : (wid == 2) ? (100 + i) : (199 - i);
    int row = bi * LLEN + qi;
    int len = qi + 1;

    if (tid < LLEN) t_s[tid] = log_times[bi * LLEN + tid];
    __syncthreads();

    // stage this query's Qt row (732 floats) into LDS
    const float* qtrow_g = Qt_g + (size_t)row * (2 * TSPAN1);
    for (int e = lane; e < 2 * TSPAN1; e += 64) qt_s[wid][e] = qtrow_g[e];

    // bucket table for this query
    int tq = t_s[qi];
    for (int k = lane; k < len; k += 64) {
        int dt = tq - t_s[k];
        if (dt < 0) dt = -dt;
        float dtf = fminf((float)dt * (1.0f / 86400.0f), 365.0f);
        tm_s[wid][k] = (unsigned short)(int)dtf;
    }

    int h = lane >> 5;       // head
    int l5 = lane & 31;
    int cch = l5 >> 2;       // channel chunk 0..7
    int jo = l5 & 3;         // key offset in group
    float4 qv = ((const float4*)(Q + row * DD))[h * 8 + cch];
    const float4* K4 = (const float4*)(Keff + (size_t)bi * LLEN * DD);
    const float scale = 0.17677669529663687f;  // 1/sqrt(32)

    // phase 1: scores, 4 keys per iteration
    for (int k0 = 0; k0 < len; k0 += 4) {
        int k = k0 + jo;
        int kc = (k < len) ? k : (len - 1);
        int bucket = tm_s[wid][kc];
        float4 kv = K4[kc * 16 + h * 8 + cch];
        float p = qv.x * kv.x + qv.y * kv.y + qv.z * kv.z + qv.w * kv.w;
        p += __shfl_xor(p, 4);
        p += __shfl_xor(p, 8);
        p += __shfl_xor(p, 16);   // full 32-dot for (h, key k)
        float s = (p + qt_s[wid][h * TSPAN1 + bucket]) * scale;
        if (cch == 0 && k < len) sc[wid][h][k] = s;
    }

    // phase 2: softmax (lanes 0..31 head 0, 32..63 head 1; same wave)
    {
        float m = -INFINITY;
        for (int k = l5; k < len; k += 32) m = fmaxf(m, sc[wid][h][k]);
        m = halfMax(m);
        float s = 0.0f;
        for (int k = l5; k < len; k += 32) {
            float e = expf(sc[wid][h][k] - m);
            sc[wid][h][k] = e;
            s += e;
        }
        s = halfSum(s);
        float inv = 1.0f / s;
        for (int k = l5; k < len; k += 32) sc[wid][h][k] *= inv;
    }

    // phase 3: out[d] = sum_k A[h][k] * (V_eff[k][d] + tV[bucket[k]][d])
    const float* Vb = Veff + (size_t)bi * LLEN * DD + lane;
    const float* tVl = tV_emb + lane;
    float acc0 = 0.0f, acc1 = 0.0f, acc2 = 0.0f, acc3 = 0.0f;
    int k = 0;
    for (; k + 4 <= len; k += 4) {
        int b0 = tm_s[wid][k + 0];
        int b1 = tm_s[wid][k + 1];
        int b2 = tm_s[wid][k + 2];
        int b3 = tm_s[wid][k + 3];
        float a0 = sc[wid][h][k + 0];
        float a1 = sc[wid][h][k + 1];
        float a2 = sc[wid][h][k + 2];
        float a3 = sc[wid][h][k + 3];
        acc0 = fmaf(a0, Vb[(k + 0) * DD] + tVl[b0 * DD], acc0);
        acc1 = fmaf(a1, Vb[(k + 1) * DD] + tVl[b1 * DD], acc1);
        acc2 = fmaf(a2, Vb[(k + 2) * DD] + tVl[b2 * DD], acc2);
        acc3 = fmaf(a3, Vb[(k + 3) * DD] + tVl[b3 * DD], acc3);
    }
    for (; k < len; ++k) {
        int b0 = tm_s[wid][k];
        acc0 = fmaf(sc[wid][h][k], Vb[k * DD] + tVl[b0 * DD], acc0);
    }
    out[row * DD + lane] = (acc0 + acc1) + (acc2 + acc3);
}

// MID + fused qt: addln_ffn(layer i) + ln_qkv(layer i+1) + qt tail.
__global__ void mid_kernel(const float* __restrict__ qin,
                           const float* __restrict__ att,
                           const float* __restrict__ g2, const float* __restrict__ b2ln,
                           const float* __restrict__ W1, const float* __restrict__ b1v,
                           const float* __restrict__ W2, const float* __restrict__ b2v,
                           const int* __restrict__ log_ids,
                           const float* __restrict__ g1n, const float* __restrict__ b1n,
                           const float* __restrict__ Wq, const float* __restrict__ bq,
                           const float* __restrict__ Wk, const float* __restrict__ bk,
                           const float* __restrict__ Wv, const float* __restrict__ bv,
                           const float* __restrict__ posK,
                           const float* __restrict__ posV,
                           const float* __restrict__ tK_emb,
                           float* __restrict__ q,
                           float* __restrict__ Q, float* __restrict__ K,
                           float* __restrict__ V,
                           float* __restrict__ Qt_g) {
    __shared__ float xs[4][DD], hs[4][DD], qs[4][DD], Qsh[4][DD];
    int tid = threadIdx.x;
    int wid = tid >> 6, d = tid & 63;
    int row = blockIdx.x * 4 + wid;
    int l = row % LLEN;
    // --- addln + FFN ---
    float v = qin[row * DD + d] + att[row * DD + d];
    float m = waveSum(v) * (1.0f / 64.0f);
    float c = v - m;
    float var = waveSum(c * c) * (1.0f / 64.0f);
    float xv = (c / sqrtf(var + 1e-8f)) * g2[d] + b2ln[d];
    xs[wid][d] = xv;
    float a = rowdot(W1, d, xs[wid], b1v[d]);
    hs[wid][d] = fmaxf(a, 0.0f);
    float o = rowdot(W2, d, hs[wid], b2v[d]);
    float res = xv + o;
    if (log_ids[row] == 0) res = 0.0f;
    // --- next layer: LN1 + QKV projection ---
    float m2 = waveSum(res) * (1.0f / 64.0f);
    float c2 = res - m2;
    float var2 = waveSum(c2 * c2) * (1.0f / 64.0f);
    float qv = (c2 / sqrtf(var2 + 1e-8f)) * g1n[d] + b1n[d];
    qs[wid][d] = qv;
    xs[wid][d] = res;
    q[row * DD + d] = qv;
    float aq = rowdot(Wq, d, qs[wid], bq[d]);
    float ak = rowdot(Wk, d, xs[wid], bk[d]);
    float av = rowdot(Wv, d, xs[wid], bv[d]);
    Q[row * DD + d] = aq;
    K[row * DD + d] = ak + posK[l * DD + d];
    V[row * DD + d] = av + posV[l * DD + d];
    Qsh[wid][d] = aq;
    __syncthreads();
    qt_tail(Qsh, tK_emb, Qt_g, blockIdx.x * 4);
}

// END: addln_ffn(last layer) fused with final LN + logits. 4 rows/block.
__global__ void end_kernel(const float* __restrict__ qin,
                           const float* __restrict__ att,
                           const float* __restrict__ g2, const float* __restrict__ b2ln,
                           const float* __restrict__ W1, const float* __restrict__ b1v,
                           const float* __restrict__ W2, const float* __restrict__ b2v,
                           const int* __restrict__ log_ids,
                           const float* __restrict__ lnf_g, const float* __restrict__ lnf_b,
                           const float* __restrict__ item_emb,
                           const int* __restrict__ pos_ids,
                           const int* __restrict__ neg_ids,
                           float* __restrict__ out) {
    __shared__ float xs[4][DD], hs[4][DD];
    int tid = threadIdx.x;
    int wid = tid >> 6, d = tid & 63;
    int row = blockIdx.x * 4 + wid;
    float v = qin[row * DD + d] + att[row * DD + d];
    float m = waveSum(v) * (1.0f / 64.0f);
    float c = v - m;
    float var = waveSum(c * c) * (1.0f / 64.0f);
    float xv = (c / sqrtf(var + 1e-8f)) * g2[d] + b2ln[d];
    xs[wid][d] = xv;
    float a = rowdot(W1, d, xs[wid], b1v[d]);
    hs[wid][d] = fmaxf(a, 0.0f);
    float o = rowdot(W2, d, hs[wid], b2v[d]);
    float res = xv + o;
    if (log_ids[row] == 0) res = 0.0f;
    // --- final LN + logits ---
    float m2 = waveSum(res) * (1.0f / 64.0f);
    float c2 = res - m2;
    float var2 = waveSum(c2 * c2) * (1.0f / 64.0f);
    float f = (c2 / sqrtf(var2 + 1e-8f)) * lnf_g[d] + lnf_b[d];
    int pid = pos_ids[row];
    int nid = neg_ids[row];
    float p = waveSum(f * item_emb[pid * DD + d]);
    float n = waveSum(f * item_emb[nid * DD + d]);
    if (d == 0) {
        out[row] = p;
        out[BB * LLEN + row] = n;
    }
}

extern "C" void kernel_launch(void* const* d_in, const int* in_sizes, int n_in,
                              void* d_out, int out_size, void* d_ws, size_t ws_size,
                              hipStream_t stream) {
    const int* log_ids = (const int*)d_in[0];
    const int* log_times = (const int*)d_in[1];
    const int* pos_ids = (const int*)d_in[2];
    const int* neg_ids = (const int*)d_in[3];
    const float* item_emb = (const float*)d_in[4];
    const float* posK = (const float*)d_in[5];
    const float* posV = (const float*)d_in[6];
    const float* tK_emb = (const float*)d_in[7];
    const float* tV_emb = (const float*)d_in[8];
    const float* ln1_g = (const float*)d_in[9];
    const float* ln1_b = (const float*)d_in[10];
    const float* Wq = (const float*)d_in[11];
    const float* bq = (const float*)d_in[12];
    const float* Wk = (const float*)d_in[13];
    const float* bk = (const float*)d_in[14];
    const float* Wv = (const float*)d_in[15];
    const float* bv = (const float*)d_in[16];
    const float* ln2_g = (const float*)d_in[17];
    const float* ln2_b = (const float*)d_in[18];
    const float* W1 = (const float*)d_in[19];
    const float* b1 = (const float*)d_in[20];
    const float* W2 = (const float*)d_in[21];
    const float* b2 = (const float*)d_in[22];
    const float* lnf_g = (const float*)d_in[23];
    const float* lnf_b = (const float*)d_in[24];

    float* ws = (float*)d_ws;
    float* q = ws;                        // ln1 output (residual)
    float* Qb = q + BLD;
    float* Kb = Qb + BLD;
    float* Vb = Kb + BLD;
    float* att = Vb + BLD;
    float* Qt = att + BLD;                // [6400][732]

    const int nrow = BB * LLEN;           // 6400
    const int DD2 = DD * DD;

    // layer 0 entry (embed + qt fused)
    ln_qkv_kernel<<<nrow / 4, 256, 0, stream>>>(log_ids, item_emb,
                                                ln1_g, ln1_b,
                                                Wq, bq, Wk, bk, Wv, bv,
                                                posK, posV, tK_emb,
                                                q, Qb, Kb, Vb, Qt);
    attn_kernel<<<BB * 50, 256, 0, stream>>>(Qb, Kb, Vb, log_times, Qt, tV_emb, att);

    // layer 0 tail + layer 1 entry (+ qt fused)
    mid_kernel<<<nrow / 4, 256, 0, stream>>>(q, att,
                                             ln2_g, ln2_b,
                                             W1, b1, W2, b2,
                                             log_ids,
                                             ln1_g + DD, ln1_b + DD,
                                             Wq + DD2, bq + DD,
                                             Wk + DD2, bk + DD,
                                             Wv + DD2, bv + DD,
                                             posK, posV, tK_emb,
                                             q, Qb, Kb, Vb, Qt);
    attn_kernel<<<BB * 50, 256, 0, stream>>>(Qb, Kb, Vb, log_times, Qt, tV_emb, att);

    // layer 1 tail + final logits
    end_kernel<<<nrow / 4, 256, 0, stream>>>(q, att,
                                             ln2_g + DD, ln2_b + DD,
                                             W1 + DD2, b1 + DD, W2 + DD2, b2 + DD,
                                             log_ids,
                                             lnf_g, lnf_b, item_emb,
                                             pos_ids, neg_ids, (float*)d_out);
}